// Round 9
// baseline (509.090 us; speedup 1.0000x reference)
//
#include <hip/hip_runtime.h>
#include <stdint.h>

// Actor_attf_single — MI355X (gfx950)
// R18: R17 + occupancy push into the <=64-VGPR band. Ledger:
//   R13 291us fp32 batch3/4 | R16 230us dot2 batch3/4 (busy 328K, stall 224K)
//   R17 199us dot2 + role-split (busy 324K, stall 153K, VGPR 92 -> 4 w/SIMD)
// VGPR 92 sits in the 65-128 band = 4 waves/SIMD; stalls (weight s_load
// drains + input latency) need more TLP. R18 forces the 64 band -> 8 w/SIMD:
//   - __launch_bounds__(256, 8): hard cap 64 VGPR
//   - batches NE=2 everywhere (enc[2][16] = 32 regs; more passes, but
//     s_loads don't consume VALU slots and 8 waves hide the drains)
//   - self_out packed to h2[8] right after self-encode (-8 regs); score
//     dot = 8 pkrtz(enc) + 8 fdot2 (instruction-neutral vs 16 fmaf).
//     acc/softmax/LN stay fp32, entity order unchanged.
// Tripwire: WRITE_SIZE > 10MB => allocator spilled, revert direction.
// absmax gate has proven headroom (0.00390625 bit-identical across fp32
// and fp16 variants — dominant error is in the reference).

#define LN_EPS 1e-5f

typedef _Float16 h2 __attribute__((ext_vector_type(2)));

struct Weights {
  const float* __restrict__ en_W1; const float* __restrict__ en_b1;
  const float* __restrict__ en_W2; const float* __restrict__ en_b2;
  const float* __restrict__ oa_W1; const float* __restrict__ oa_b1;
  const float* __restrict__ oa_W2; const float* __restrict__ oa_b2;
  const float* __restrict__ go_W1; const float* __restrict__ go_b1;
  const float* __restrict__ go_W2; const float* __restrict__ go_b2;
  const float* __restrict__ oa_g;  const float* __restrict__ oa_b;
  const float* __restrict__ go_g;  const float* __restrict__ go_b;
  const float* __restrict__ a_W1;  const float* __restrict__ a_b1;
  const float* __restrict__ a_W2;  const float* __restrict__ a_b2;
  const float* __restrict__ a_W3;  const float* __restrict__ a_b3;
};

// workspace layout (uint32 = packed half2 units)
constexpr int P_EN_W1 = 0;     //  64
constexpr int P_EN_W2 = 64;    // 256
constexpr int P_OA_W1 = 320;   //  64
constexpr int P_OA_W2 = 384;   // 256
constexpr int P_GO_W1 = 640;   //  32
constexpr int P_GO_W2 = 672;   // 256
constexpr int P_A_W1  = 928;   // 768
constexpr int P_A_W2  = 1696;  // 512
constexpr int P_A_W3  = 2208;  //  32
// total 2240 u32 = 8960 bytes

__device__ __forceinline__ float2 ld2(const float* __restrict__ p) {
  return *reinterpret_cast<const float2*>(p);
}
__device__ __forceinline__ uint32_t pack_rne(float a, float b) {
  h2 v; v.x = (_Float16)a; v.y = (_Float16)b;
  return __builtin_bit_cast(uint32_t, v);
}
__device__ __forceinline__ h2 asH2(uint32_t u) { return __builtin_bit_cast(h2, u); }
__device__ __forceinline__ float fdot2(h2 a, h2 b, float c) {
  return __builtin_amdgcn_fdot2(a, b, c, false);
}
__device__ __forceinline__ h2 pkrtz(float a, float b) {
  return __builtin_bit_cast(h2, __builtin_amdgcn_cvt_pkrtz(a, b));
}

// ---- prep: fp32 weights -> packed half2 in workspace ---------------------
__global__ void prep_weights(Weights W, uint32_t* __restrict__ ws) {
  const int t = threadIdx.x;
  if (t < 32) {
    ws[P_EN_W1 + t]      = pack_rne(W.en_W1[t],      W.en_W1[32 + t]);
    ws[P_EN_W1 + 32 + t] = pack_rne(W.en_W1[64 + t], W.en_W1[96 + t]);
    ws[P_OA_W1 + t]      = pack_rne(W.oa_W1[t],      W.oa_W1[32 + t]);
    ws[P_OA_W1 + 32 + t] = pack_rne(W.oa_W1[64 + t], W.oa_W1[96 + t]);
    ws[P_GO_W1 + t]      = pack_rne(W.go_W1[t],      W.go_W1[32 + t]);
  }
  {
    int jp = t >> 4, d = t & 15;
    ws[P_EN_W2 + t] = pack_rne(W.en_W2[(2*jp)*16 + d], W.en_W2[(2*jp+1)*16 + d]);
    ws[P_OA_W2 + t] = pack_rne(W.oa_W2[(2*jp)*16 + d], W.oa_W2[(2*jp+1)*16 + d]);
    ws[P_GO_W2 + t] = pack_rne(W.go_W2[(2*jp)*16 + d], W.go_W2[(2*jp+1)*16 + d]);
  }
  for (int i = t; i < 768; i += 256) {
    int cp = i >> 5, j = i & 31;
    ws[P_A_W1 + i] = pack_rne(W.a_W1[(2*cp)*32 + j], W.a_W1[(2*cp+1)*32 + j]);
  }
  for (int i = t; i < 512; i += 256) {
    int cp = i >> 5, j = i & 31;
    ws[P_A_W2 + i] = pack_rne(W.a_W2[(2*cp)*32 + j], W.a_W2[(2*cp+1)*32 + j]);
  }
  if (t < 32) {
    int cp = t >> 1, o = t & 1;
    ws[P_A_W3 + t] = pack_rne(W.a_W3[(2*cp)*2 + o], W.a_W3[(2*cp+1)*2 + o]);
  }
}

// ---- one batch of NE "other" entities starting at k0 ---------------------
template<int NE>
__device__ __forceinline__ void oa_batch(const float* __restrict__ srow, int k0,
                                         const Weights& W,
                                         const uint32_t* __restrict__ wsu,
                                         const h2 (&selfh)[8],
                                         float (&acc)[16], float& m, float& l) {
  h2 a01[NE], a23[NE];
#pragma unroll
  for (int e = 0; e < NE; ++e) {
    float2 x = ld2(srow + 4  + 2*(k0 + e));
    float2 y = ld2(srow + 34 + 2*(k0 + e));
    a01[e] = pkrtz(x.x, x.y);
    a23[e] = pkrtz(y.x, y.y);
  }
  float enc[NE][16];
#pragma unroll
  for (int d = 0; d < 16; ++d) {
    float b2 = W.oa_b2[d];
#pragma unroll
    for (int e = 0; e < NE; ++e) enc[e][d] = b2;
  }
#pragma unroll
  for (int jp = 0; jp < 16; ++jp) {
    const int j0 = 2*jp, j1 = 2*jp + 1;
    const float b10 = W.oa_b1[j0], b11 = W.oa_b1[j1];
    const h2 wA0 = asH2(wsu[P_OA_W1 + j0]), wB0 = asH2(wsu[P_OA_W1 + 32 + j0]);
    const h2 wA1 = asH2(wsu[P_OA_W1 + j1]), wB1 = asH2(wsu[P_OA_W1 + 32 + j1]);
    h2 hh[NE];
#pragma unroll
    for (int e = 0; e < NE; ++e) {
      float h0 = fmaxf(fdot2(a01[e], wA0, fdot2(a23[e], wB0, b10)), 0.f);
      float h1 = fmaxf(fdot2(a01[e], wA1, fdot2(a23[e], wB1, b11)), 0.f);
      hh[e] = pkrtz(h0, h1);
    }
#pragma unroll
    for (int d = 0; d < 16; ++d) {
      const h2 wd = asH2(wsu[P_OA_W2 + jp*16 + d]);
#pragma unroll
      for (int e = 0; e < NE; ++e) enc[e][d] = fdot2(hh[e], wd, enc[e][d]);
    }
  }
  // per-entity epilogue, strictly in entity order; score via packed dot
#pragma unroll
  for (int e = 0; e < NE; ++e) {
    float s = 0.f;
#pragma unroll
    for (int c = 0; c < 8; ++c) {
      enc[e][2*c]   = fmaxf(enc[e][2*c],   0.f);
      enc[e][2*c+1] = fmaxf(enc[e][2*c+1], 0.f);
      s = fdot2(selfh[c], pkrtz(enc[e][2*c], enc[e][2*c+1]), s);
    }
    s *= 0.25f;
    float mn = fmaxf(m, s);
    float alpha = __expf(m - mn), w = __expf(s - mn);
    l = fmaf(l, alpha, w);
#pragma unroll
    for (int d = 0; d < 16; ++d) acc[d] = fmaf(acc[d], alpha, w * enc[e][d]);
    m = mn;
  }
}

// ---- one batch of NE "food" entities starting at k0 ----------------------
template<int NE>
__device__ __forceinline__ void go_batch(const float* __restrict__ srow, int k0,
                                         const Weights& W,
                                         const uint32_t* __restrict__ wsu,
                                         const h2 (&selfh)[8],
                                         float (&acc)[16], float& m, float& l) {
  h2 ah[NE];
#pragma unroll
  for (int e = 0; e < NE; ++e) {
    float2 x = ld2(srow + 64 + 2*(k0 + e));
    ah[e] = pkrtz(x.x, x.y);
  }
  float enc[NE][16];
#pragma unroll
  for (int d = 0; d < 16; ++d) {
    float b2 = W.go_b2[d];
#pragma unroll
    for (int e = 0; e < NE; ++e) enc[e][d] = b2;
  }
#pragma unroll
  for (int jp = 0; jp < 16; ++jp) {
    const int j0 = 2*jp, j1 = 2*jp + 1;
    const float b10 = W.go_b1[j0], b11 = W.go_b1[j1];
    const h2 w0 = asH2(wsu[P_GO_W1 + j0]);
    const h2 w1 = asH2(wsu[P_GO_W1 + j1]);
    h2 hh[NE];
#pragma unroll
    for (int e = 0; e < NE; ++e) {
      float h0 = fmaxf(fdot2(ah[e], w0, b10), 0.f);
      float h1 = fmaxf(fdot2(ah[e], w1, b11), 0.f);
      hh[e] = pkrtz(h0, h1);
    }
#pragma unroll
    for (int d = 0; d < 16; ++d) {
      const h2 wd = asH2(wsu[P_GO_W2 + jp*16 + d]);
#pragma unroll
      for (int e = 0; e < NE; ++e) enc[e][d] = fdot2(hh[e], wd, enc[e][d]);
    }
  }
  // per-entity epilogue, strictly in entity order; score via packed dot
#pragma unroll
  for (int e = 0; e < NE; ++e) {
    float s = 0.f;
#pragma unroll
    for (int c = 0; c < 8; ++c) {
      enc[e][2*c]   = fmaxf(enc[e][2*c],   0.f);
      enc[e][2*c+1] = fmaxf(enc[e][2*c+1], 0.f);
      s = fdot2(selfh[c], pkrtz(enc[e][2*c], enc[e][2*c+1]), s);
    }
    s *= 0.25f;
    float mn = fmaxf(m, s);
    float alpha = __expf(m - mn), w = __expf(s - mn);
    l = fmaf(l, alpha, w);
#pragma unroll
    for (int d = 0; d < 16; ++d) acc[d] = fmaf(acc[d], alpha, w * enc[e][d]);
    m = mn;
  }
}

__global__ __launch_bounds__(256, 8)
void actor_fwd(const float* __restrict__ s_input, Weights W,
               const uint32_t* __restrict__ wsu,
               float* __restrict__ out, int bsz) {
  const int lane    = threadIdx.x & 63;
  const int wv      = threadIdx.x >> 6;      // 0..3
  const int pairIdx = wv >> 1;               // 0..1  (64-row group)
  const int role    = wv & 1;                // 0: other+head, 1: food
  int row = blockIdx.x * 128 + pairIdx * 64 + lane;
  row = min(row, bsz - 1);
  const float* __restrict__ srow = s_input + (size_t)row * 96;

  __shared__ float fpool[2][64][17];         // +1 pad: conflict-free

  // ---------------- self encoder (both roles): 4 -> 32 -> 16, relu --------
  // result kept PACKED (h2 x8) to stay under the 64-VGPR cap
  h2 selfh[8];
  {
    float2 p01 = ld2(srow + 0);
    float2 p23 = ld2(srow + 2);
    h2 a01 = pkrtz(p01.x, p01.y);
    h2 a23 = pkrtz(p23.x, p23.y);
    float self_out[16];
#pragma unroll
    for (int d = 0; d < 16; ++d) self_out[d] = W.en_b2[d];
#pragma unroll
    for (int jp = 0; jp < 16; ++jp) {
      const int j0 = 2*jp, j1 = 2*jp + 1;
      float h0 = fmaxf(fdot2(a01, asH2(wsu[P_EN_W1 + j0]),
                     fdot2(a23, asH2(wsu[P_EN_W1 + 32 + j0]), W.en_b1[j0])), 0.f);
      float h1 = fmaxf(fdot2(a01, asH2(wsu[P_EN_W1 + j1]),
                     fdot2(a23, asH2(wsu[P_EN_W1 + 32 + j1]), W.en_b1[j1])), 0.f);
      h2 hh = pkrtz(h0, h1);
#pragma unroll
      for (int d = 0; d < 16; ++d)
        self_out[d] = fdot2(hh, asH2(wsu[P_EN_W2 + jp*16 + d]), self_out[d]);
    }
#pragma unroll
    for (int c = 0; c < 8; ++c)
      selfh[c] = pkrtz(fmaxf(self_out[2*c], 0.f), fmaxf(self_out[2*c+1], 0.f));
  }

  float other_pool[16];

  if (role == 0) {
    // ------- other agents: 15 entities = 7x2 + 1 -------------------------
    float m = -3.0e38f, l = 0.f, acc[16];
#pragma unroll
    for (int d = 0; d < 16; ++d) acc[d] = 0.f;
#pragma unroll 1
    for (int k0 = 0; k0 < 14; k0 += 2)
      oa_batch<2>(srow, k0, W, wsu, selfh, acc, m, l);
    oa_batch<1>(srow, 14, W, wsu, selfh, acc, m, l);

    float inv = 1.f / l;
    float mu = 0.f;
#pragma unroll
    for (int d = 0; d < 16; ++d) { acc[d] *= inv; mu += acc[d]; }
    mu *= (1.f / 16.f);
    float var = 0.f;
#pragma unroll
    for (int d = 0; d < 16; ++d) { float x = acc[d] - mu; var = fmaf(x, x, var); }
    var *= (1.f / 16.f);
    float rstd = rsqrtf(var + LN_EPS);
#pragma unroll
    for (int d = 0; d < 16; ++d)
      other_pool[d] = fmaxf(fmaf((acc[d] - mu) * rstd, W.oa_g[d], W.oa_b[d]), 0.f);
  } else {
    // ------- food: 16 entities = 8x2 -> LDS ------------------------------
    float m = -3.0e38f, l = 0.f, acc[16];
#pragma unroll
    for (int d = 0; d < 16; ++d) acc[d] = 0.f;
#pragma unroll 1
    for (int k0 = 0; k0 < 16; k0 += 2)
      go_batch<2>(srow, k0, W, wsu, selfh, acc, m, l);

    float inv = 1.f / l;
    float mu = 0.f;
#pragma unroll
    for (int d = 0; d < 16; ++d) { acc[d] *= inv; mu += acc[d]; }
    mu *= (1.f / 16.f);
    float var = 0.f;
#pragma unroll
    for (int d = 0; d < 16; ++d) { float x = acc[d] - mu; var = fmaf(x, x, var); }
    var *= (1.f / 16.f);
    float rstd = rsqrtf(var + LN_EPS);
#pragma unroll
    for (int d = 0; d < 16; ++d) {
      float fp = fmaxf(fmaf((acc[d] - mu) * rstd, W.go_g[d], W.go_b[d]), 0.f);
      fpool[pairIdx][lane][d] = fp;
    }
  }

  __syncthreads();
  if (role != 0) return;

  // ------- action head (role 0): 48 -> 32 -> 32 -> 2, via dot2 -----------
  h2 mh[24];
#pragma unroll
  for (int c = 0; c < 8; ++c) mh[c] = selfh[c];
#pragma unroll
  for (int c = 0; c < 8; ++c) {
    float f0 = fpool[pairIdx][lane][2*c], f1 = fpool[pairIdx][lane][2*c+1];
    mh[8 + c] = pkrtz(f0, f1);
  }
#pragma unroll
  for (int c = 0; c < 8; ++c) mh[16 + c] = pkrtz(other_pool[2*c], other_pool[2*c+1]);

  float h1v[32];
#pragma unroll
  for (int j = 0; j < 32; ++j) h1v[j] = W.a_b1[j];
#pragma unroll
  for (int cp = 0; cp < 24; ++cp) {
    h2 v = mh[cp];
#pragma unroll
    for (int j = 0; j < 32; ++j)
      h1v[j] = fdot2(v, asH2(wsu[P_A_W1 + cp*32 + j]), h1v[j]);
  }
#pragma unroll
  for (int j = 0; j < 32; ++j) h1v[j] = fmaxf(h1v[j], 0.01f * h1v[j]);  // leaky

  h2 hh1[16];
#pragma unroll
  for (int c = 0; c < 16; ++c) hh1[c] = pkrtz(h1v[2*c], h1v[2*c+1]);

  float h2v[32];
#pragma unroll
  for (int j = 0; j < 32; ++j) h2v[j] = W.a_b2[j];
#pragma unroll
  for (int cp = 0; cp < 16; ++cp) {
    h2 v = hh1[cp];
#pragma unroll
    for (int j = 0; j < 32; ++j)
      h2v[j] = fdot2(v, asH2(wsu[P_A_W2 + cp*32 + j]), h2v[j]);
  }
#pragma unroll
  for (int j = 0; j < 32; ++j) h2v[j] = fmaxf(h2v[j], 0.01f * h2v[j]);

  h2 hh2[16];
#pragma unroll
  for (int c = 0; c < 16; ++c) hh2[c] = pkrtz(h2v[2*c], h2v[2*c+1]);

  float o0 = W.a_b3[0], o1 = W.a_b3[1];
#pragma unroll
  for (int cp = 0; cp < 16; ++cp) {
    o0 = fdot2(hh2[cp], asH2(wsu[P_A_W3 + cp*2 + 0]), o0);
    o1 = fdot2(hh2[cp], asH2(wsu[P_A_W3 + cp*2 + 1]), o1);
  }
  o0 = tanhf(o0);
  o1 = tanhf(o1);

  reinterpret_cast<float2*>(out)[row] = make_float2(o0, o1);
}

extern "C" void kernel_launch(void* const* d_in, const int* in_sizes, int n_in,
                              void* d_out, int out_size, void* d_ws, size_t ws_size,
                              hipStream_t stream) {
  const float* s_input = (const float*)d_in[0];
  Weights W;
  W.en_W1 = (const float*)d_in[1];  W.en_b1 = (const float*)d_in[2];
  W.en_W2 = (const float*)d_in[3];  W.en_b2 = (const float*)d_in[4];
  W.oa_W1 = (const float*)d_in[5];  W.oa_b1 = (const float*)d_in[6];
  W.oa_W2 = (const float*)d_in[7];  W.oa_b2 = (const float*)d_in[8];
  W.go_W1 = (const float*)d_in[9];  W.go_b1 = (const float*)d_in[10];
  W.go_W2 = (const float*)d_in[11]; W.go_b2 = (const float*)d_in[12];
  W.oa_g  = (const float*)d_in[13]; W.oa_b  = (const float*)d_in[14];
  W.go_g  = (const float*)d_in[15]; W.go_b  = (const float*)d_in[16];
  W.a_W1  = (const float*)d_in[17]; W.a_b1  = (const float*)d_in[18];
  W.a_W2  = (const float*)d_in[19]; W.a_b2  = (const float*)d_in[20];
  W.a_W3  = (const float*)d_in[21]; W.a_b3  = (const float*)d_in[22];

  uint32_t* wsu = (uint32_t*)d_ws;   // needs 8960 bytes
  prep_weights<<<1, 256, 0, stream>>>(W, wsu);

  const int bsz = in_sizes[0] / 96;          // 262144
  const int blocks = (bsz + 127) / 128;      // 128 rows/block: 2 groups x 2 roles
  actor_fwd<<<blocks, 256, 0, stream>>>(s_input, W, wsu, (float*)d_out, bsz);
}

// Round 10
// 311.503 us; speedup vs baseline: 1.6343x; 1.6343x over previous
//
#include <hip/hip_runtime.h>
#include <stdint.h>

// Actor_attf_single — MI355X (gfx950)
// R19: revert R18, base = R17 (199us best) + input-prefetch pipeline.
// Ledger:
//   R16 230us dot2 batch3/4 (busy 328K, stall 224K)
//   R17 199us dot2 + role-split (busy 324K, stall 153K, VGPR 92, 4 w/SIMD)
//   R18 370us launch_bounds(256,8): allocator went to VGPR=32, 1.4GB spill
//       traffic. RULE (3 strikes: R11/R14/R18): min-waves > 2 => destructive
//       spill. This kernel lives in the 65-128 VGPR / 4-wave band.
// R19 lever: per-wave exposed latency, not occupancy. Weight s_load drains
// are unfixable (SMEM out-of-order). Input loads at each batch top ARE
// fixable: software-prefetch batch k+1's inputs before batch k's j-loop
// (~400cyc of weight-FMA cover); batch 0 prefetched before self-encoder.
// float4 loads where 16B-aligned (self col0; food cols 64+8k). Math is
// BITWISE-IDENTICAL to R17 (only load scheduling changes).
// Tripwire: WRITE_SIZE > 6MB => spill, revert. absmax must stay 0.00390625.

#define LN_EPS 1e-5f

typedef _Float16 h2 __attribute__((ext_vector_type(2)));

struct Weights {
  const float* __restrict__ en_W1; const float* __restrict__ en_b1;
  const float* __restrict__ en_W2; const float* __restrict__ en_b2;
  const float* __restrict__ oa_W1; const float* __restrict__ oa_b1;
  const float* __restrict__ oa_W2; const float* __restrict__ oa_b2;
  const float* __restrict__ go_W1; const float* __restrict__ go_b1;
  const float* __restrict__ go_W2; const float* __restrict__ go_b2;
  const float* __restrict__ oa_g;  const float* __restrict__ oa_b;
  const float* __restrict__ go_g;  const float* __restrict__ go_b;
  const float* __restrict__ a_W1;  const float* __restrict__ a_b1;
  const float* __restrict__ a_W2;  const float* __restrict__ a_b2;
  const float* __restrict__ a_W3;  const float* __restrict__ a_b3;
};

// workspace layout (uint32 = packed half2 units)
constexpr int P_EN_W1 = 0;     //  64
constexpr int P_EN_W2 = 64;    // 256
constexpr int P_OA_W1 = 320;   //  64
constexpr int P_OA_W2 = 384;   // 256
constexpr int P_GO_W1 = 640;   //  32
constexpr int P_GO_W2 = 672;   // 256
constexpr int P_A_W1  = 928;   // 768
constexpr int P_A_W2  = 1696;  // 512
constexpr int P_A_W3  = 2208;  //  32
// total 2240 u32 = 8960 bytes

__device__ __forceinline__ float2 ld2(const float* __restrict__ p) {
  return *reinterpret_cast<const float2*>(p);
}
__device__ __forceinline__ float4 ld4(const float* __restrict__ p) {
  return *reinterpret_cast<const float4*>(p);
}
__device__ __forceinline__ uint32_t pack_rne(float a, float b) {
  h2 v; v.x = (_Float16)a; v.y = (_Float16)b;
  return __builtin_bit_cast(uint32_t, v);
}
__device__ __forceinline__ h2 asH2(uint32_t u) { return __builtin_bit_cast(h2, u); }
__device__ __forceinline__ float fdot2(h2 a, h2 b, float c) {
  return __builtin_amdgcn_fdot2(a, b, c, false);
}
__device__ __forceinline__ h2 pkrtz(float a, float b) {
  return __builtin_bit_cast(h2, __builtin_amdgcn_cvt_pkrtz(a, b));
}

// ---- prep: fp32 weights -> packed half2 in workspace ---------------------
__global__ void prep_weights(Weights W, uint32_t* __restrict__ ws) {
  const int t = threadIdx.x;
  if (t < 32) {
    ws[P_EN_W1 + t]      = pack_rne(W.en_W1[t],      W.en_W1[32 + t]);
    ws[P_EN_W1 + 32 + t] = pack_rne(W.en_W1[64 + t], W.en_W1[96 + t]);
    ws[P_OA_W1 + t]      = pack_rne(W.oa_W1[t],      W.oa_W1[32 + t]);
    ws[P_OA_W1 + 32 + t] = pack_rne(W.oa_W1[64 + t], W.oa_W1[96 + t]);
    ws[P_GO_W1 + t]      = pack_rne(W.go_W1[t],      W.go_W1[32 + t]);
  }
  {
    int jp = t >> 4, d = t & 15;
    ws[P_EN_W2 + t] = pack_rne(W.en_W2[(2*jp)*16 + d], W.en_W2[(2*jp+1)*16 + d]);
    ws[P_OA_W2 + t] = pack_rne(W.oa_W2[(2*jp)*16 + d], W.oa_W2[(2*jp+1)*16 + d]);
    ws[P_GO_W2 + t] = pack_rne(W.go_W2[(2*jp)*16 + d], W.go_W2[(2*jp+1)*16 + d]);
  }
  for (int i = t; i < 768; i += 256) {
    int cp = i >> 5, j = i & 31;
    ws[P_A_W1 + i] = pack_rne(W.a_W1[(2*cp)*32 + j], W.a_W1[(2*cp+1)*32 + j]);
  }
  for (int i = t; i < 512; i += 256) {
    int cp = i >> 5, j = i & 31;
    ws[P_A_W2 + i] = pack_rne(W.a_W2[(2*cp)*32 + j], W.a_W2[(2*cp+1)*32 + j]);
  }
  if (t < 32) {
    int cp = t >> 1, o = t & 1;
    ws[P_A_W3 + t] = pack_rne(W.a_W3[(2*cp)*2 + o], W.a_W3[(2*cp+1)*2 + o]);
  }
}

// ---- one batch of 3 "other" entities (inputs pre-loaded) -----------------
__device__ __forceinline__ void oa_batch3(const float2 (&i01)[3],
                                          const float2 (&i23)[3],
                                          const Weights& W,
                                          const uint32_t* __restrict__ wsu,
                                          const float (&self_out)[16],
                                          float (&acc)[16], float& m, float& l) {
  h2 a01[3], a23[3];
#pragma unroll
  for (int e = 0; e < 3; ++e) {
    a01[e] = pkrtz(i01[e].x, i01[e].y);
    a23[e] = pkrtz(i23[e].x, i23[e].y);
  }
  float enc[3][16];
#pragma unroll
  for (int d = 0; d < 16; ++d) {
    float b2 = W.oa_b2[d];
#pragma unroll
    for (int e = 0; e < 3; ++e) enc[e][d] = b2;
  }
#pragma unroll
  for (int jp = 0; jp < 16; ++jp) {
    const int j0 = 2*jp, j1 = 2*jp + 1;
    const float b10 = W.oa_b1[j0], b11 = W.oa_b1[j1];
    const h2 wA0 = asH2(wsu[P_OA_W1 + j0]), wB0 = asH2(wsu[P_OA_W1 + 32 + j0]);
    const h2 wA1 = asH2(wsu[P_OA_W1 + j1]), wB1 = asH2(wsu[P_OA_W1 + 32 + j1]);
    h2 hh[3];
#pragma unroll
    for (int e = 0; e < 3; ++e) {
      float h0 = fmaxf(fdot2(a01[e], wA0, fdot2(a23[e], wB0, b10)), 0.f);
      float h1 = fmaxf(fdot2(a01[e], wA1, fdot2(a23[e], wB1, b11)), 0.f);
      hh[e] = pkrtz(h0, h1);
    }
#pragma unroll
    for (int d = 0; d < 16; ++d) {
      const h2 wd = asH2(wsu[P_OA_W2 + jp*16 + d]);
#pragma unroll
      for (int e = 0; e < 3; ++e) enc[e][d] = fdot2(hh[e], wd, enc[e][d]);
    }
  }
  // per-entity epilogue, strictly in entity order (fp32, verbatim R17)
#pragma unroll
  for (int e = 0; e < 3; ++e) {
    float s = 0.f;
#pragma unroll
    for (int d = 0; d < 16; ++d) {
      enc[e][d] = fmaxf(enc[e][d], 0.f);
      s = fmaf(self_out[d], enc[e][d], s);
    }
    s *= 0.25f;
    float mn = fmaxf(m, s);
    float alpha = __expf(m - mn), w = __expf(s - mn);
    l = fmaf(l, alpha, w);
#pragma unroll
    for (int d = 0; d < 16; ++d) acc[d] = fmaf(acc[d], alpha, w * enc[e][d]);
    m = mn;
  }
}

// ---- one batch of 4 "food" entities (inputs pre-loaded as 2x float4) -----
__device__ __forceinline__ void go_batch4(const float4 q0, const float4 q1,
                                          const Weights& W,
                                          const uint32_t* __restrict__ wsu,
                                          const float (&self_out)[16],
                                          float (&acc)[16], float& m, float& l) {
  h2 ah[4];
  ah[0] = pkrtz(q0.x, q0.y);
  ah[1] = pkrtz(q0.z, q0.w);
  ah[2] = pkrtz(q1.x, q1.y);
  ah[3] = pkrtz(q1.z, q1.w);
  float enc[4][16];
#pragma unroll
  for (int d = 0; d < 16; ++d) {
    float b2 = W.go_b2[d];
#pragma unroll
    for (int e = 0; e < 4; ++e) enc[e][d] = b2;
  }
#pragma unroll
  for (int jp = 0; jp < 16; ++jp) {
    const int j0 = 2*jp, j1 = 2*jp + 1;
    const float b10 = W.go_b1[j0], b11 = W.go_b1[j1];
    const h2 w0 = asH2(wsu[P_GO_W1 + j0]);
    const h2 w1 = asH2(wsu[P_GO_W1 + j1]);
    h2 hh[4];
#pragma unroll
    for (int e = 0; e < 4; ++e) {
      float h0 = fmaxf(fdot2(ah[e], w0, b10), 0.f);
      float h1 = fmaxf(fdot2(ah[e], w1, b11), 0.f);
      hh[e] = pkrtz(h0, h1);
    }
#pragma unroll
    for (int d = 0; d < 16; ++d) {
      const h2 wd = asH2(wsu[P_GO_W2 + jp*16 + d]);
#pragma unroll
      for (int e = 0; e < 4; ++e) enc[e][d] = fdot2(hh[e], wd, enc[e][d]);
    }
  }
  // per-entity epilogue, strictly in entity order (fp32, verbatim R17)
#pragma unroll
  for (int e = 0; e < 4; ++e) {
    float s = 0.f;
#pragma unroll
    for (int d = 0; d < 16; ++d) {
      enc[e][d] = fmaxf(enc[e][d], 0.f);
      s = fmaf(self_out[d], enc[e][d], s);
    }
    s *= 0.25f;
    float mn = fmaxf(m, s);
    float alpha = __expf(m - mn), w = __expf(s - mn);
    l = fmaf(l, alpha, w);
#pragma unroll
    for (int d = 0; d < 16; ++d) acc[d] = fmaf(acc[d], alpha, w * enc[e][d]);
    m = mn;
  }
}

__global__ __launch_bounds__(256, 2)
void actor_fwd(const float* __restrict__ s_input, Weights W,
               const uint32_t* __restrict__ wsu,
               float* __restrict__ out, int bsz) {
  const int lane    = threadIdx.x & 63;
  const int wv      = threadIdx.x >> 6;      // 0..3
  const int pairIdx = wv >> 1;               // 0..1  (64-row group)
  const int role    = wv & 1;                // 0: other+head, 1: food
  int row = blockIdx.x * 128 + pairIdx * 64 + lane;
  row = min(row, bsz - 1);
  const float* __restrict__ srow = s_input + (size_t)row * 96;

  __shared__ float fpool[2][64][17];         // +1 pad: conflict-free

  // ---- prefetch: self inputs (both) + batch-0 inputs (per role) ---------
  float4 pself = ld4(srow);                  // cols 0..3, 16B-aligned
  float2 pre01[3], pre23[3];                 // oa pipeline regs (role 0)
  float4 preq0, preq1;                       // go pipeline regs (role 1)
  if (role == 0) {
#pragma unroll
    for (int e = 0; e < 3; ++e) {
      pre01[e] = ld2(srow + 4  + 2*e);
      pre23[e] = ld2(srow + 34 + 2*e);
    }
  } else {
    preq0 = ld4(srow + 64);                  // cols 64..67, aligned
    preq1 = ld4(srow + 68);
  }

  // ---------------- self encoder (both roles): 4 -> 32 -> 16, relu --------
  float self_out[16];
  {
    h2 a01 = pkrtz(pself.x, pself.y);
    h2 a23 = pkrtz(pself.z, pself.w);
#pragma unroll
    for (int d = 0; d < 16; ++d) self_out[d] = W.en_b2[d];
#pragma unroll
    for (int jp = 0; jp < 16; ++jp) {
      const int j0 = 2*jp, j1 = 2*jp + 1;
      float h0 = fmaxf(fdot2(a01, asH2(wsu[P_EN_W1 + j0]),
                     fdot2(a23, asH2(wsu[P_EN_W1 + 32 + j0]), W.en_b1[j0])), 0.f);
      float h1 = fmaxf(fdot2(a01, asH2(wsu[P_EN_W1 + j1]),
                     fdot2(a23, asH2(wsu[P_EN_W1 + 32 + j1]), W.en_b1[j1])), 0.f);
      h2 hh = pkrtz(h0, h1);
#pragma unroll
      for (int d = 0; d < 16; ++d)
        self_out[d] = fdot2(hh, asH2(wsu[P_EN_W2 + jp*16 + d]), self_out[d]);
    }
#pragma unroll
    for (int d = 0; d < 16; ++d) self_out[d] = fmaxf(self_out[d], 0.f);
  }

  float other_pool[16];

  if (role == 0) {
    // ------- other agents: 15 entities = 5 passes of 3, prefetched -------
    float m = -3.0e38f, l = 0.f, acc[16];
#pragma unroll
    for (int d = 0; d < 16; ++d) acc[d] = 0.f;
#pragma unroll 1
    for (int k0 = 0; k0 < 15; k0 += 3) {
      float2 c01[3], c23[3];
#pragma unroll
      for (int e = 0; e < 3; ++e) { c01[e] = pre01[e]; c23[e] = pre23[e]; }
      if (k0 + 3 < 15) {
#pragma unroll
        for (int e = 0; e < 3; ++e) {
          pre01[e] = ld2(srow + 4  + 2*(k0 + 3 + e));
          pre23[e] = ld2(srow + 34 + 2*(k0 + 3 + e));
        }
      }
      oa_batch3(c01, c23, W, wsu, self_out, acc, m, l);
    }

    float inv = 1.f / l;
    float mu = 0.f;
#pragma unroll
    for (int d = 0; d < 16; ++d) { acc[d] *= inv; mu += acc[d]; }
    mu *= (1.f / 16.f);
    float var = 0.f;
#pragma unroll
    for (int d = 0; d < 16; ++d) { float x = acc[d] - mu; var = fmaf(x, x, var); }
    var *= (1.f / 16.f);
    float rstd = rsqrtf(var + LN_EPS);
#pragma unroll
    for (int d = 0; d < 16; ++d)
      other_pool[d] = fmaxf(fmaf((acc[d] - mu) * rstd, W.oa_g[d], W.oa_b[d]), 0.f);
  } else {
    // ------- food: 16 entities = 4 passes of 4 (float4), prefetched ------
    float m = -3.0e38f, l = 0.f, acc[16];
#pragma unroll
    for (int d = 0; d < 16; ++d) acc[d] = 0.f;
#pragma unroll 1
    for (int k0 = 0; k0 < 16; k0 += 4) {
      float4 c0 = preq0, c1 = preq1;
      if (k0 + 4 < 16) {
        preq0 = ld4(srow + 64 + 2*(k0 + 4));
        preq1 = ld4(srow + 68 + 2*(k0 + 4));
      }
      go_batch4(c0, c1, W, wsu, self_out, acc, m, l);
    }

    float inv = 1.f / l;
    float mu = 0.f;
#pragma unroll
    for (int d = 0; d < 16; ++d) { acc[d] *= inv; mu += acc[d]; }
    mu *= (1.f / 16.f);
    float var = 0.f;
#pragma unroll
    for (int d = 0; d < 16; ++d) { float x = acc[d] - mu; var = fmaf(x, x, var); }
    var *= (1.f / 16.f);
    float rstd = rsqrtf(var + LN_EPS);
#pragma unroll
    for (int d = 0; d < 16; ++d) {
      float fp = fmaxf(fmaf((acc[d] - mu) * rstd, W.go_g[d], W.go_b[d]), 0.f);
      fpool[pairIdx][lane][d] = fp;
    }
  }

  __syncthreads();
  if (role != 0) return;

  // ------- action head (role 0): 48 -> 32 -> 32 -> 2, via dot2 -----------
  float food_pool[16];
#pragma unroll
  for (int d = 0; d < 16; ++d) food_pool[d] = fpool[pairIdx][lane][d];

  h2 mh[24];
#pragma unroll
  for (int c = 0; c < 8; ++c) mh[c]      = pkrtz(self_out[2*c],  self_out[2*c+1]);
#pragma unroll
  for (int c = 0; c < 8; ++c) mh[8 + c]  = pkrtz(food_pool[2*c], food_pool[2*c+1]);
#pragma unroll
  for (int c = 0; c < 8; ++c) mh[16 + c] = pkrtz(other_pool[2*c], other_pool[2*c+1]);

  float h1v[32];
#pragma unroll
  for (int j = 0; j < 32; ++j) h1v[j] = W.a_b1[j];
#pragma unroll
  for (int cp = 0; cp < 24; ++cp) {
    h2 v = mh[cp];
#pragma unroll
    for (int j = 0; j < 32; ++j)
      h1v[j] = fdot2(v, asH2(wsu[P_A_W1 + cp*32 + j]), h1v[j]);
  }
#pragma unroll
  for (int j = 0; j < 32; ++j) h1v[j] = fmaxf(h1v[j], 0.01f * h1v[j]);  // leaky

  h2 hh1[16];
#pragma unroll
  for (int c = 0; c < 16; ++c) hh1[c] = pkrtz(h1v[2*c], h1v[2*c+1]);

  float h2v[32];
#pragma unroll
  for (int j = 0; j < 32; ++j) h2v[j] = W.a_b2[j];
#pragma unroll
  for (int cp = 0; cp < 16; ++cp) {
    h2 v = hh1[cp];
#pragma unroll
    for (int j = 0; j < 32; ++j)
      h2v[j] = fdot2(v, asH2(wsu[P_A_W2 + cp*32 + j]), h2v[j]);
  }
#pragma unroll
  for (int j = 0; j < 32; ++j) h2v[j] = fmaxf(h2v[j], 0.01f * h2v[j]);

  h2 hh2[16];
#pragma unroll
  for (int c = 0; c < 16; ++c) hh2[c] = pkrtz(h2v[2*c], h2v[2*c+1]);

  float o0 = W.a_b3[0], o1 = W.a_b3[1];
#pragma unroll
  for (int cp = 0; cp < 16; ++cp) {
    o0 = fdot2(hh2[cp], asH2(wsu[P_A_W3 + cp*2 + 0]), o0);
    o1 = fdot2(hh2[cp], asH2(wsu[P_A_W3 + cp*2 + 1]), o1);
  }
  o0 = tanhf(o0);
  o1 = tanhf(o1);

  reinterpret_cast<float2*>(out)[row] = make_float2(o0, o1);
}

extern "C" void kernel_launch(void* const* d_in, const int* in_sizes, int n_in,
                              void* d_out, int out_size, void* d_ws, size_t ws_size,
                              hipStream_t stream) {
  const float* s_input = (const float*)d_in[0];
  Weights W;
  W.en_W1 = (const float*)d_in[1];  W.en_b1 = (const float*)d_in[2];
  W.en_W2 = (const float*)d_in[3];  W.en_b2 = (const float*)d_in[4];
  W.oa_W1 = (const float*)d_in[5];  W.oa_b1 = (const float*)d_in[6];
  W.oa_W2 = (const float*)d_in[7];  W.oa_b2 = (const float*)d_in[8];
  W.go_W1 = (const float*)d_in[9];  W.go_b1 = (const float*)d_in[10];
  W.go_W2 = (const float*)d_in[11]; W.go_b2 = (const float*)d_in[12];
  W.oa_g  = (const float*)d_in[13]; W.oa_b  = (const float*)d_in[14];
  W.go_g  = (const float*)d_in[15]; W.go_b  = (const float*)d_in[16];
  W.a_W1  = (const float*)d_in[17]; W.a_b1  = (const float*)d_in[18];
  W.a_W2  = (const float*)d_in[19]; W.a_b2  = (const float*)d_in[20];
  W.a_W3  = (const float*)d_in[21]; W.a_b3  = (const float*)d_in[22];

  uint32_t* wsu = (uint32_t*)d_ws;   // needs 8960 bytes
  prep_weights<<<1, 256, 0, stream>>>(W, wsu);

  const int bsz = in_sizes[0] / 96;          // 262144
  const int blocks = (bsz + 127) / 128;      // 128 rows/block: 2 groups x 2 roles
  actor_fwd<<<blocks, 256, 0, stream>>>(s_input, W, wsu, (float*)d_out, bsz);
}

// Round 11
// 295.470 us; speedup vs baseline: 1.7230x; 1.0543x over previous
//
#include <hip/hip_runtime.h>
#include <stdint.h>

// Actor_attf_single — MI355X (gfx950)
// R20: R19 + LDS routing for the oa/go pass-loop weight stream. Ledger:
//   R17 199us (stall 153K)  R19 173.5us (input prefetch; stall 81K, busy
//   335K, VALUBusy 80.5%, VGPR 84). Remaining stall ~= weight s_load
//   drains: SMEM is out-of-order -> every weight wait is lgkmcnt(0) full
//   drain, several per pass, 9 passes/wave.
// R10 (LDS-everything) exploded VGPRs; R20 removes its 3 causes:
//   (a) weights pre-packed h2 (half the bytes of R10's fp32)
//   (b) vector ds_read_b128/b64: 6 reads/jp, not 20 scalar
//   (c) #pragma unroll 2 bounds the scheduler's read-hoist window
// ds_read is IN-ORDER -> compiler emits counted lgkmcnt(N) (m97 evidence)
// -> weight reads pipeline under the 63-VALU jp body instead of draining.
// Scope: ONLY oa/go L1+L2+b1 (672 u32 = 2.7KB LDS). Self-encoder, head,
// b2 stay SMEM (once-per-wave, amortized). Same weight bits -> math
// BITWISE-IDENTICAL to R19; absmax must stay 0.00390625.
// Tripwires: VGPR > 128 (band drop) or WRITE_SIZE > 6MB (spill) => revert.

#define LN_EPS 1e-5f

typedef _Float16 h2 __attribute__((ext_vector_type(2)));

struct Weights {
  const float* __restrict__ en_W1; const float* __restrict__ en_b1;
  const float* __restrict__ en_W2; const float* __restrict__ en_b2;
  const float* __restrict__ oa_W1; const float* __restrict__ oa_b1;
  const float* __restrict__ oa_W2; const float* __restrict__ oa_b2;
  const float* __restrict__ go_W1; const float* __restrict__ go_b1;
  const float* __restrict__ go_W2; const float* __restrict__ go_b2;
  const float* __restrict__ oa_g;  const float* __restrict__ oa_b;
  const float* __restrict__ go_g;  const float* __restrict__ go_b;
  const float* __restrict__ a_W1;  const float* __restrict__ a_b1;
  const float* __restrict__ a_W2;  const float* __restrict__ a_b2;
  const float* __restrict__ a_W3;  const float* __restrict__ a_b3;
};

// workspace layout (uint32 = packed half2 units)
constexpr int P_EN_W1 = 0;     //  64
constexpr int P_EN_W2 = 64;    // 256
constexpr int P_OA_W1 = 320;   //  64
constexpr int P_OA_W2 = 384;   // 256
constexpr int P_GO_W1 = 640;   //  32
constexpr int P_GO_W2 = 672;   // 256
constexpr int P_A_W1  = 928;   // 768
constexpr int P_A_W2  = 1696;  // 512
constexpr int P_A_W3  = 2208;  //  32
// total 2240 u32 = 8960 bytes

// LDS weight-pool offsets (u32 units; uint4 arrays 16B-aligned)
constexpr int L_OA_L1 = 0;     //  64: [jp*4+c] = {wA0,wA1,wB0,wB1}
constexpr int L_OA_L2 = 64;    // 256: [jp*16+d]
constexpr int L_GO_L2 = 320;   // 256: [jp*16+d]
constexpr int L_GO_L1 = 576;   //  32: [jp*2+{0,1}]   (8B-aligned)
constexpr int L_OA_B1 = 608;   //  32 floats: [jp*2+{0,1}]
constexpr int L_GO_B1 = 640;   //  32 floats
constexpr int L_TOTAL = 672;   // 2688 bytes

__device__ __forceinline__ float2 ld2(const float* __restrict__ p) {
  return *reinterpret_cast<const float2*>(p);
}
__device__ __forceinline__ float4 ld4(const float* __restrict__ p) {
  return *reinterpret_cast<const float4*>(p);
}
__device__ __forceinline__ uint32_t pack_rne(float a, float b) {
  h2 v; v.x = (_Float16)a; v.y = (_Float16)b;
  return __builtin_bit_cast(uint32_t, v);
}
__device__ __forceinline__ h2 asH2(uint32_t u) { return __builtin_bit_cast(h2, u); }
__device__ __forceinline__ float fdot2(h2 a, h2 b, float c) {
  return __builtin_amdgcn_fdot2(a, b, c, false);
}
__device__ __forceinline__ h2 pkrtz(float a, float b) {
  return __builtin_bit_cast(h2, __builtin_amdgcn_cvt_pkrtz(a, b));
}

// ---- prep: fp32 weights -> packed half2 in workspace ---------------------
__global__ void prep_weights(Weights W, uint32_t* __restrict__ ws) {
  const int t = threadIdx.x;
  if (t < 32) {
    ws[P_EN_W1 + t]      = pack_rne(W.en_W1[t],      W.en_W1[32 + t]);
    ws[P_EN_W1 + 32 + t] = pack_rne(W.en_W1[64 + t], W.en_W1[96 + t]);
    ws[P_OA_W1 + t]      = pack_rne(W.oa_W1[t],      W.oa_W1[32 + t]);
    ws[P_OA_W1 + 32 + t] = pack_rne(W.oa_W1[64 + t], W.oa_W1[96 + t]);
    ws[P_GO_W1 + t]      = pack_rne(W.go_W1[t],      W.go_W1[32 + t]);
  }
  {
    int jp = t >> 4, d = t & 15;
    ws[P_EN_W2 + t] = pack_rne(W.en_W2[(2*jp)*16 + d], W.en_W2[(2*jp+1)*16 + d]);
    ws[P_OA_W2 + t] = pack_rne(W.oa_W2[(2*jp)*16 + d], W.oa_W2[(2*jp+1)*16 + d]);
    ws[P_GO_W2 + t] = pack_rne(W.go_W2[(2*jp)*16 + d], W.go_W2[(2*jp+1)*16 + d]);
  }
  for (int i = t; i < 768; i += 256) {
    int cp = i >> 5, j = i & 31;
    ws[P_A_W1 + i] = pack_rne(W.a_W1[(2*cp)*32 + j], W.a_W1[(2*cp+1)*32 + j]);
  }
  for (int i = t; i < 512; i += 256) {
    int cp = i >> 5, j = i & 31;
    ws[P_A_W2 + i] = pack_rne(W.a_W2[(2*cp)*32 + j], W.a_W2[(2*cp+1)*32 + j]);
  }
  if (t < 32) {
    int cp = t >> 1, o = t & 1;
    ws[P_A_W3 + t] = pack_rne(W.a_W3[(2*cp)*2 + o], W.a_W3[(2*cp+1)*2 + o]);
  }
}

// ---- one batch of 3 "other" entities (inputs pre-loaded, weights LDS) ----
__device__ __forceinline__ void oa_batch3(const float2 (&i01)[3],
                                          const float2 (&i23)[3],
                                          const Weights& W,
                                          const uint32_t* __restrict__ swl,
                                          const float (&self_out)[16],
                                          float (&acc)[16], float& m, float& l) {
  h2 a01[3], a23[3];
#pragma unroll
  for (int e = 0; e < 3; ++e) {
    a01[e] = pkrtz(i01[e].x, i01[e].y);
    a23[e] = pkrtz(i23[e].x, i23[e].y);
  }
  float enc[3][16];
#pragma unroll
  for (int d = 0; d < 16; ++d) {
    float b2 = W.oa_b2[d];
#pragma unroll
    for (int e = 0; e < 3; ++e) enc[e][d] = b2;
  }
#pragma unroll 2
  for (int jp = 0; jp < 16; ++jp) {
    const uint4 l1 = *reinterpret_cast<const uint4*>(&swl[L_OA_L1 + jp*4]);
    const float2 bb = *reinterpret_cast<const float2*>(
        &reinterpret_cast<const float*>(swl)[L_OA_B1 + jp*2]);
    const uint4 q0 = *reinterpret_cast<const uint4*>(&swl[L_OA_L2 + jp*16 + 0]);
    const uint4 q1 = *reinterpret_cast<const uint4*>(&swl[L_OA_L2 + jp*16 + 4]);
    const uint4 q2 = *reinterpret_cast<const uint4*>(&swl[L_OA_L2 + jp*16 + 8]);
    const uint4 q3 = *reinterpret_cast<const uint4*>(&swl[L_OA_L2 + jp*16 + 12]);
    const h2 wA0 = asH2(l1.x), wA1 = asH2(l1.y);
    const h2 wB0 = asH2(l1.z), wB1 = asH2(l1.w);
    h2 hh[3];
#pragma unroll
    for (int e = 0; e < 3; ++e) {
      float h0 = fmaxf(fdot2(a01[e], wA0, fdot2(a23[e], wB0, bb.x)), 0.f);
      float h1 = fmaxf(fdot2(a01[e], wA1, fdot2(a23[e], wB1, bb.y)), 0.f);
      hh[e] = pkrtz(h0, h1);
    }
    const uint32_t l2[16] = {q0.x, q0.y, q0.z, q0.w, q1.x, q1.y, q1.z, q1.w,
                             q2.x, q2.y, q2.z, q2.w, q3.x, q3.y, q3.z, q3.w};
#pragma unroll
    for (int d = 0; d < 16; ++d) {
      const h2 wd = asH2(l2[d]);
#pragma unroll
      for (int e = 0; e < 3; ++e) enc[e][d] = fdot2(hh[e], wd, enc[e][d]);
    }
  }
  // per-entity epilogue, strictly in entity order (fp32, verbatim R19)
#pragma unroll
  for (int e = 0; e < 3; ++e) {
    float s = 0.f;
#pragma unroll
    for (int d = 0; d < 16; ++d) {
      enc[e][d] = fmaxf(enc[e][d], 0.f);
      s = fmaf(self_out[d], enc[e][d], s);
    }
    s *= 0.25f;
    float mn = fmaxf(m, s);
    float alpha = __expf(m - mn), w = __expf(s - mn);
    l = fmaf(l, alpha, w);
#pragma unroll
    for (int d = 0; d < 16; ++d) acc[d] = fmaf(acc[d], alpha, w * enc[e][d]);
    m = mn;
  }
}

// ---- one batch of 4 "food" entities (inputs pre-loaded, weights LDS) -----
__device__ __forceinline__ void go_batch4(const float4 q0i, const float4 q1i,
                                          const Weights& W,
                                          const uint32_t* __restrict__ swl,
                                          const float (&self_out)[16],
                                          float (&acc)[16], float& m, float& l) {
  h2 ah[4];
  ah[0] = pkrtz(q0i.x, q0i.y);
  ah[1] = pkrtz(q0i.z, q0i.w);
  ah[2] = pkrtz(q1i.x, q1i.y);
  ah[3] = pkrtz(q1i.z, q1i.w);
  float enc[4][16];
#pragma unroll
  for (int d = 0; d < 16; ++d) {
    float b2 = W.go_b2[d];
#pragma unroll
    for (int e = 0; e < 4; ++e) enc[e][d] = b2;
  }
#pragma unroll 2
  for (int jp = 0; jp < 16; ++jp) {
    const uint2 g1 = *reinterpret_cast<const uint2*>(&swl[L_GO_L1 + jp*2]);
    const float2 bb = *reinterpret_cast<const float2*>(
        &reinterpret_cast<const float*>(swl)[L_GO_B1 + jp*2]);
    const uint4 q0 = *reinterpret_cast<const uint4*>(&swl[L_GO_L2 + jp*16 + 0]);
    const uint4 q1 = *reinterpret_cast<const uint4*>(&swl[L_GO_L2 + jp*16 + 4]);
    const uint4 q2 = *reinterpret_cast<const uint4*>(&swl[L_GO_L2 + jp*16 + 8]);
    const uint4 q3 = *reinterpret_cast<const uint4*>(&swl[L_GO_L2 + jp*16 + 12]);
    const h2 w0 = asH2(g1.x), w1 = asH2(g1.y);
    h2 hh[4];
#pragma unroll
    for (int e = 0; e < 4; ++e) {
      float h0 = fmaxf(fdot2(ah[e], w0, bb.x), 0.f);
      float h1 = fmaxf(fdot2(ah[e], w1, bb.y), 0.f);
      hh[e] = pkrtz(h0, h1);
    }
    const uint32_t l2[16] = {q0.x, q0.y, q0.z, q0.w, q1.x, q1.y, q1.z, q1.w,
                             q2.x, q2.y, q2.z, q2.w, q3.x, q3.y, q3.z, q3.w};
#pragma unroll
    for (int d = 0; d < 16; ++d) {
      const h2 wd = asH2(l2[d]);
#pragma unroll
      for (int e = 0; e < 4; ++e) enc[e][d] = fdot2(hh[e], wd, enc[e][d]);
    }
  }
  // per-entity epilogue, strictly in entity order (fp32, verbatim R19)
#pragma unroll
  for (int e = 0; e < 4; ++e) {
    float s = 0.f;
#pragma unroll
    for (int d = 0; d < 16; ++d) {
      enc[e][d] = fmaxf(enc[e][d], 0.f);
      s = fmaf(self_out[d], enc[e][d], s);
    }
    s *= 0.25f;
    float mn = fmaxf(m, s);
    float alpha = __expf(m - mn), w = __expf(s - mn);
    l = fmaf(l, alpha, w);
#pragma unroll
    for (int d = 0; d < 16; ++d) acc[d] = fmaf(acc[d], alpha, w * enc[e][d]);
    m = mn;
  }
}

__global__ __launch_bounds__(256, 2)
void actor_fwd(const float* __restrict__ s_input, Weights W,
               const uint32_t* __restrict__ wsu,
               float* __restrict__ out, int bsz) {
  const int lane    = threadIdx.x & 63;
  const int wv      = threadIdx.x >> 6;      // 0..3
  const int pairIdx = wv >> 1;               // 0..1  (64-row group)
  const int role    = wv & 1;                // 0: other+head, 1: food
  int row = blockIdx.x * 128 + pairIdx * 64 + lane;
  row = min(row, bsz - 1);
  const float* __restrict__ srow = s_input + (size_t)row * 96;

  __shared__ __align__(16) uint32_t swl[L_TOTAL];  // weight pool (2.7KB)
  __shared__ float fpool[2][64][17];               // +1 pad: conflict-free

  // ---- one-time weight staging: wsu (global, packed) -> LDS -------------
  {
    const int t = threadIdx.x;
    if (t < 64) {
      int jp = t >> 2, c = t & 3;
      swl[L_OA_L1 + t] = wsu[P_OA_W1 + (c & 2) * 16 + 2 * jp + (c & 1)];
    }
    swl[L_OA_L2 + t] = wsu[P_OA_W2 + t];           // 256 contiguous
    swl[L_GO_L2 + t] = wsu[P_GO_W2 + t];           // 256 contiguous
    if (t < 32) {
      swl[L_GO_L1 + t] = wsu[P_GO_W1 + t];
      reinterpret_cast<float*>(swl)[L_OA_B1 + t] = W.oa_b1[t];
      reinterpret_cast<float*>(swl)[L_GO_B1 + t] = W.go_b1[t];
    }
  }

  // ---- prefetch: self inputs (both) + batch-0 inputs (per role) ---------
  float4 pself = ld4(srow);                  // cols 0..3, 16B-aligned
  float2 pre01[3], pre23[3];                 // oa pipeline regs (role 0)
  float4 preq0, preq1;                       // go pipeline regs (role 1)
  if (role == 0) {
#pragma unroll
    for (int e = 0; e < 3; ++e) {
      pre01[e] = ld2(srow + 4  + 2*e);
      pre23[e] = ld2(srow + 34 + 2*e);
    }
  } else {
    preq0 = ld4(srow + 64);                  // cols 64..67, aligned
    preq1 = ld4(srow + 68);
  }

  __syncthreads();                           // staging visible to all waves

  // ---------------- self encoder (both roles): 4 -> 32 -> 16, relu --------
  float self_out[16];
  {
    h2 a01 = pkrtz(pself.x, pself.y);
    h2 a23 = pkrtz(pself.z, pself.w);
#pragma unroll
    for (int d = 0; d < 16; ++d) self_out[d] = W.en_b2[d];
#pragma unroll
    for (int jp = 0; jp < 16; ++jp) {
      const int j0 = 2*jp, j1 = 2*jp + 1;
      float h0 = fmaxf(fdot2(a01, asH2(wsu[P_EN_W1 + j0]),
                     fdot2(a23, asH2(wsu[P_EN_W1 + 32 + j0]), W.en_b1[j0])), 0.f);
      float h1 = fmaxf(fdot2(a01, asH2(wsu[P_EN_W1 + j1]),
                     fdot2(a23, asH2(wsu[P_EN_W1 + 32 + j1]), W.en_b1[j1])), 0.f);
      h2 hh = pkrtz(h0, h1);
#pragma unroll
      for (int d = 0; d < 16; ++d)
        self_out[d] = fdot2(hh, asH2(wsu[P_EN_W2 + jp*16 + d]), self_out[d]);
    }
#pragma unroll
    for (int d = 0; d < 16; ++d) self_out[d] = fmaxf(self_out[d], 0.f);
  }

  float other_pool[16];

  if (role == 0) {
    // ------- other agents: 15 entities = 5 passes of 3, prefetched -------
    float m = -3.0e38f, l = 0.f, acc[16];
#pragma unroll
    for (int d = 0; d < 16; ++d) acc[d] = 0.f;
#pragma unroll 1
    for (int k0 = 0; k0 < 15; k0 += 3) {
      float2 c01[3], c23[3];
#pragma unroll
      for (int e = 0; e < 3; ++e) { c01[e] = pre01[e]; c23[e] = pre23[e]; }
      if (k0 + 3 < 15) {
#pragma unroll
        for (int e = 0; e < 3; ++e) {
          pre01[e] = ld2(srow + 4  + 2*(k0 + 3 + e));
          pre23[e] = ld2(srow + 34 + 2*(k0 + 3 + e));
        }
      }
      oa_batch3(c01, c23, W, swl, self_out, acc, m, l);
    }

    float inv = 1.f / l;
    float mu = 0.f;
#pragma unroll
    for (int d = 0; d < 16; ++d) { acc[d] *= inv; mu += acc[d]; }
    mu *= (1.f / 16.f);
    float var = 0.f;
#pragma unroll
    for (int d = 0; d < 16; ++d) { float x = acc[d] - mu; var = fmaf(x, x, var); }
    var *= (1.f / 16.f);
    float rstd = rsqrtf(var + LN_EPS);
#pragma unroll
    for (int d = 0; d < 16; ++d)
      other_pool[d] = fmaxf(fmaf((acc[d] - mu) * rstd, W.oa_g[d], W.oa_b[d]), 0.f);
  } else {
    // ------- food: 16 entities = 4 passes of 4 (float4), prefetched ------
    float m = -3.0e38f, l = 0.f, acc[16];
#pragma unroll
    for (int d = 0; d < 16; ++d) acc[d] = 0.f;
#pragma unroll 1
    for (int k0 = 0; k0 < 16; k0 += 4) {
      float4 c0 = preq0, c1 = preq1;
      if (k0 + 4 < 16) {
        preq0 = ld4(srow + 64 + 2*(k0 + 4));
        preq1 = ld4(srow + 68 + 2*(k0 + 4));
      }
      go_batch4(c0, c1, W, swl, self_out, acc, m, l);
    }

    float inv = 1.f / l;
    float mu = 0.f;
#pragma unroll
    for (int d = 0; d < 16; ++d) { acc[d] *= inv; mu += acc[d]; }
    mu *= (1.f / 16.f);
    float var = 0.f;
#pragma unroll
    for (int d = 0; d < 16; ++d) { float x = acc[d] - mu; var = fmaf(x, x, var); }
    var *= (1.f / 16.f);
    float rstd = rsqrtf(var + LN_EPS);
#pragma unroll
    for (int d = 0; d < 16; ++d) {
      float fp = fmaxf(fmaf((acc[d] - mu) * rstd, W.go_g[d], W.go_b[d]), 0.f);
      fpool[pairIdx][lane][d] = fp;
    }
  }

  __syncthreads();
  if (role != 0) return;

  // ------- action head (role 0): 48 -> 32 -> 32 -> 2, via dot2 -----------
  float food_pool[16];
#pragma unroll
  for (int d = 0; d < 16; ++d) food_pool[d] = fpool[pairIdx][lane][d];

  h2 mh[24];
#pragma unroll
  for (int c = 0; c < 8; ++c) mh[c]      = pkrtz(self_out[2*c],  self_out[2*c+1]);
#pragma unroll
  for (int c = 0; c < 8; ++c) mh[8 + c]  = pkrtz(food_pool[2*c], food_pool[2*c+1]);
#pragma unroll
  for (int c = 0; c < 8; ++c) mh[16 + c] = pkrtz(other_pool[2*c], other_pool[2*c+1]);

  float h1v[32];
#pragma unroll
  for (int j = 0; j < 32; ++j) h1v[j] = W.a_b1[j];
#pragma unroll
  for (int cp = 0; cp < 24; ++cp) {
    h2 v = mh[cp];
#pragma unroll
    for (int j = 0; j < 32; ++j)
      h1v[j] = fdot2(v, asH2(wsu[P_A_W1 + cp*32 + j]), h1v[j]);
  }
#pragma unroll
  for (int j = 0; j < 32; ++j) h1v[j] = fmaxf(h1v[j], 0.01f * h1v[j]);  // leaky

  h2 hh1[16];
#pragma unroll
  for (int c = 0; c < 16; ++c) hh1[c] = pkrtz(h1v[2*c], h1v[2*c+1]);

  float h2v[32];
#pragma unroll
  for (int j = 0; j < 32; ++j) h2v[j] = W.a_b2[j];
#pragma unroll
  for (int cp = 0; cp < 16; ++cp) {
    h2 v = hh1[cp];
#pragma unroll
    for (int j = 0; j < 32; ++j)
      h2v[j] = fdot2(v, asH2(wsu[P_A_W2 + cp*32 + j]), h2v[j]);
  }
#pragma unroll
  for (int j = 0; j < 32; ++j) h2v[j] = fmaxf(h2v[j], 0.01f * h2v[j]);

  h2 hh2[16];
#pragma unroll
  for (int c = 0; c < 16; ++c) hh2[c] = pkrtz(h2v[2*c], h2v[2*c+1]);

  float o0 = W.a_b3[0], o1 = W.a_b3[1];
#pragma unroll
  for (int cp = 0; cp < 16; ++cp) {
    o0 = fdot2(hh2[cp], asH2(wsu[P_A_W3 + cp*2 + 0]), o0);
    o1 = fdot2(hh2[cp], asH2(wsu[P_A_W3 + cp*2 + 1]), o1);
  }
  o0 = tanhf(o0);
  o1 = tanhf(o1);

  reinterpret_cast<float2*>(out)[row] = make_float2(o0, o1);
}

extern "C" void kernel_launch(void* const* d_in, const int* in_sizes, int n_in,
                              void* d_out, int out_size, void* d_ws, size_t ws_size,
                              hipStream_t stream) {
  const float* s_input = (const float*)d_in[0];
  Weights W;
  W.en_W1 = (const float*)d_in[1];  W.en_b1 = (const float*)d_in[2];
  W.en_W2 = (const float*)d_in[3];  W.en_b2 = (const float*)d_in[4];
  W.oa_W1 = (const float*)d_in[5];  W.oa_b1 = (const float*)d_in[6];
  W.oa_W2 = (const float*)d_in[7];  W.oa_b2 = (const float*)d_in[8];
  W.go_W1 = (const float*)d_in[9];  W.go_b1 = (const float*)d_in[10];
  W.go_W2 = (const float*)d_in[11]; W.go_b2 = (const float*)d_in[12];
  W.oa_g  = (const float*)d_in[13]; W.oa_b  = (const float*)d_in[14];
  W.go_g  = (const float*)d_in[15]; W.go_b  = (const float*)d_in[16];
  W.a_W1  = (const float*)d_in[17]; W.a_b1  = (const float*)d_in[18];
  W.a_W2  = (const float*)d_in[19]; W.a_b2  = (const float*)d_in[20];
  W.a_W3  = (const float*)d_in[21]; W.a_b3  = (const float*)d_in[22];

  uint32_t* wsu = (uint32_t*)d_ws;   // needs 8960 bytes
  prep_weights<<<1, 256, 0, stream>>>(W, wsu);

  const int bsz = in_sizes[0] / 96;          // 262144
  const int blocks = (bsz + 127) / 128;      // 128 rows/block: 2 groups x 2 roles
  actor_fwd<<<blocks, 256, 0, stream>>>(s_input, W, wsu, (float*)d_out, bsz);
}